// Round 8
// baseline (455.626 us; speedup 1.0000x reference)
//
#include <hip/hip_runtime.h>
#include <cstdint>
#include <cstddef>

static constexpr int QL = 1024;   // q_len
// k_len = 2048, d_model = 1024, heads = 16, depth = 64

typedef _Float16 half8 __attribute__((ext_vector_type(8)));
typedef _Float16 half4 __attribute__((ext_vector_type(4)));
typedef float f32x4 __attribute__((ext_vector_type(4)));

// ---------------------------------------------------------------------------
// gather: A rows come from cat(mems, inputs) per batch (2048 rows/batch)
// ---------------------------------------------------------------------------
__device__ __forceinline__ const float* gemm_row_ptr(const float* A, const float* A2,
                                                     int r, int gather) {
  if (!gather) return A + (size_t)r * 1024;
  int b = r >> 11, tt = r & 2047;
  if (tt < QL) return A + ((size_t)b * QL + tt) * 1024;    // mems part
  return A2 + ((size_t)b * QL + (tt - QL)) * 1024;         // inputs part
}

// ---------------------------------------------------------------------------
// Merged fp32 -> fp16 conversion: rows 0..8191 = cat(mems,inputs) -> a16,
// rows 8192..10239 = pos_emb -> pe16.
// ---------------------------------------------------------------------------
__global__ __launch_bounds__(256) void convert_all(
    const float* __restrict__ mems, const float* __restrict__ inputs,
    const float* __restrict__ pos_emb,
    _Float16* __restrict__ a16, _Float16* __restrict__ pe16) {
  const int row = blockIdx.x;
  const int c = threadIdx.x * 4;
  if (row < 8192) {
    const float* src = gemm_row_ptr(mems, inputs, row, 1);
    float4 v = *(const float4*)(src + c);
    half4 o = { (_Float16)v.x, (_Float16)v.y, (_Float16)v.z, (_Float16)v.w };
    *(half4*)(a16 + (size_t)row * 1024 + c) = o;
  } else {
    int r2 = row - 8192;
    float4 v = *(const float4*)(pos_emb + (size_t)r2 * 1024 + c);
    half4 o = { (_Float16)v.x, (_Float16)v.y, (_Float16)v.z, (_Float16)v.w };
    *(half4*)(pe16 + (size_t)r2 * 1024 + c) = o;
  }
}

// ---------------------------------------------------------------------------
// Merged weight split: W[1024][N] -> Wt[N][2048] fp16 [k-tile: hi32|lo32].
// blockIdx.x: 0..47 -> W_w; 48..63 -> W_r; 64..79 -> W_o.
// ---------------------------------------------------------------------------
__global__ __launch_bounds__(256) void split_w3(
    const float* __restrict__ Ww, const float* __restrict__ Wr,
    const float* __restrict__ Wo, _Float16* __restrict__ wwt,
    _Float16* __restrict__ wrt, _Float16* __restrict__ wot) {
  __shared__ float T[64][65];
  const int x = blockIdx.x;
  const float* W; _Float16* Wt; int N, nbB;
  if (x < 48)      { W = Ww; Wt = wwt; N = 3072; nbB = x; }
  else if (x < 64) { W = Wr; Wt = wrt; N = 1024; nbB = x - 48; }
  else             { W = Wo; Wt = wot; N = 1024; nbB = x - 64; }
  const int nb = nbB * 64, kb = blockIdx.y * 64;
  const int t = threadIdx.x;
  {
    int row = t >> 2, c0 = (t & 3) * 16;
    const float* src = W + (size_t)(kb + row) * N + nb + c0;
#pragma unroll
    for (int c = 0; c < 16; c += 4) {
      float4 v = *(const float4*)(src + c);
      T[row][c0 + c + 0] = v.x; T[row][c0 + c + 1] = v.y;
      T[row][c0 + c + 2] = v.z; T[row][c0 + c + 3] = v.w;
    }
  }
  __syncthreads();
  {
    int nrow = t >> 2, ks = (t & 3) * 16;
    half8 hi0, hi1, lo0, lo1;
#pragma unroll
    for (int c = 0; c < 16; ++c) {
      float f = T[ks + c][nrow];
      _Float16 h = (_Float16)f;
      _Float16 l = (_Float16)(f - (float)h);
      if (c < 8) { hi0[c] = h; lo0[c] = l; } else { hi1[c - 8] = h; lo1[c - 8] = l; }
    }
    int kglob = kb + ks;
    int kt = kglob >> 5, pos = kglob & 31;
    _Float16* dst = Wt + (size_t)(nb + nrow) * 2048 + kt * 64 + pos;
    *(half8*)dst = hi0; *(half8*)(dst + 8) = hi1;
    *(half8*)(dst + 32) = lo0; *(half8*)(dst + 40) = lo1;
  }
}

// ---------------------------------------------------------------------------
// MFMA GEMM with register prefetch (unchanged from R7).
// modes 0/1: 1-term fp16. mode 2: 2-term, fp32 out.
// ---------------------------------------------------------------------------
__global__ __launch_bounds__(256) void gemm2(
    const _Float16* __restrict__ A16, const _Float16* __restrict__ Bt,
    int mode, const float* __restrict__ rwb,
    _Float16* __restrict__ d_q, _Float16* __restrict__ d_k,
    _Float16* __restrict__ d_v, float* __restrict__ d_f) {
  const int nbase = blockIdx.x * 128, mbase = blockIdx.y * 128;
  if (mode == 0 && nbase < 1024 && (mbase & 1024) == 0) return;

  __shared__ __align__(16) _Float16 As[128][40];
  __shared__ __align__(16) _Float16 Bs[128][72];
  const int t = threadIdx.x;
  const int lane = t & 63, w = t >> 6;
  const int ln = lane & 15, g = lane >> 4;
  const int wm = (w & 1) * 64, wn = (w >> 1) * 64;
  const int ar = t >> 1, aseg = (t & 1) * 16;
  const int br = t >> 1;
  const int bseg = (mode == 2) ? (t & 1) * 32 : (t & 1) * 16;
  const _Float16* arow = A16 + (size_t)(mbase + ar) * 1024 + aseg;
  const _Float16* brow = Bt + (size_t)(nbase + br) * 2048 + bseg;

  half8 pa0, pa1, pb0, pb1, pb2, pb3;
  pa0 = *(const half8*)(arow);      pa1 = *(const half8*)(arow + 8);
  pb0 = *(const half8*)(brow);      pb1 = *(const half8*)(brow + 8);
  if (mode == 2) { pb2 = *(const half8*)(brow + 16); pb3 = *(const half8*)(brow + 24); }

  f32x4 acc[4][4] = {};
  for (int kt = 0; kt < 32; ++kt) {
    __syncthreads();
    *(half8*)&As[ar][aseg] = pa0;     *(half8*)&As[ar][aseg + 8] = pa1;
    *(half8*)&Bs[br][bseg] = pb0;     *(half8*)&Bs[br][bseg + 8] = pb1;
    if (mode == 2) { *(half8*)&Bs[br][bseg + 16] = pb2; *(half8*)&Bs[br][bseg + 24] = pb3; }
    __syncthreads();
    if (kt + 1 < 32) {
      const _Float16* ap = arow + (kt + 1) * 32;
      const _Float16* bp = brow + (kt + 1) * 64;
      pa0 = *(const half8*)(ap);      pa1 = *(const half8*)(ap + 8);
      pb0 = *(const half8*)(bp);      pb1 = *(const half8*)(bp + 8);
      if (mode == 2) { pb2 = *(const half8*)(bp + 16); pb3 = *(const half8*)(bp + 24); }
    }
    half8 ah[4], bh[4], bl[4];
#pragma unroll
    for (int i = 0; i < 4; ++i)
      ah[i] = *(const half8*)&As[wm + i * 16 + ln][g * 8];
#pragma unroll
    for (int j = 0; j < 4; ++j)
      bh[j] = *(const half8*)&Bs[wn + j * 16 + ln][g * 8];
    if (mode == 2) {
#pragma unroll
      for (int j = 0; j < 4; ++j)
        bl[j] = *(const half8*)&Bs[wn + j * 16 + ln][32 + g * 8];
    }
#pragma unroll
    for (int i = 0; i < 4; ++i)
#pragma unroll
      for (int j = 0; j < 4; ++j) {
        acc[i][j] = __builtin_amdgcn_mfma_f32_16x16x32_f16(ah[i], bh[j], acc[i][j], 0, 0, 0);
        if (mode == 2)
          acc[i][j] = __builtin_amdgcn_mfma_f32_16x16x32_f16(ah[i], bl[j], acc[i][j], 0, 0, 0);
      }
  }

  if (mode == 2) {
#pragma unroll
    for (int i = 0; i < 4; ++i)
#pragma unroll
      for (int j = 0; j < 4; ++j) {
        float* cp = d_f + (size_t)(mbase + wm + i * 16 + g * 4) * 1024 + nbase + wn + j * 16 + ln;
#pragma unroll
        for (int r = 0; r < 4; ++r) cp[(size_t)r * 1024] = acc[i][j][r];
      }
    return;
  }
  if (mode == 1) {
#pragma unroll
    for (int j = 0; j < 4; ++j) {
      int n = nbase + wn + j * 16 + ln;
      int h = n >> 6, d = n & 63;
#pragma unroll
      for (int i = 0; i < 4; ++i) {
        int m0 = mbase + wm + i * 16 + g * 4;
        _Float16* rp = d_q + ((size_t)h * 2048 + m0) * 64 + d;   // d_q = r16
#pragma unroll
        for (int r = 0; r < 4; ++r) rp[(size_t)r * 64] = (_Float16)acc[i][j][r];
      }
    }
    return;
  }
  // mode 0: qkv fused scatter
#pragma unroll
  for (int j = 0; j < 4; ++j) {
    int n = nbase + wn + j * 16 + ln;
    int sec = n >> 10;              // 0=q 1=k 2=v
    int c2 = n & 1023, h = c2 >> 6, d = c2 & 63;
    float bias = (sec == 0) ? rwb[c2] : 0.f;
#pragma unroll
    for (int i = 0; i < 4; ++i) {
      int m0 = mbase + wm + i * 16 + g * 4;
      int b = m0 >> 11, tt0 = m0 & 2047;
      size_t bh = (size_t)(b * 16 + h);
#pragma unroll
      for (int r = 0; r < 4; ++r) {
        int tt = tt0 + r;
        float v = acc[i][j][r];
        if (sec == 0) {
          if (tt >= 1024)
            d_q[(bh * 1024 + (tt - 1024)) * 64 + d] = (_Float16)(v + bias);
        } else if (sec == 1) {
          d_k[(bh * 2048 + tt) * 64 + d] = (_Float16)v;
        } else {
          d_v[(bh * 64 + d) * 2048 + tt] = (_Float16)v;
        }
      }
    }
  }
}

// ---------------------------------------------------------------------------
// cdelta[h][jr] = sum_d (r_r_bias - r_w_bias)[h][d] * r16[h][jr][d]
// ---------------------------------------------------------------------------
__global__ __launch_bounds__(256) void cdelta_kernel(
    const _Float16* __restrict__ r16, const float* __restrict__ rwb,
    const float* __restrict__ rrb, float* __restrict__ cd) {
  int idx = blockIdx.x * 256 + threadIdx.x;
  int jr = idx >> 4, h = idx & 15;
  const _Float16* rp = r16 + ((size_t)h * 2048 + jr) * 64;
  const float* a = rrb + h * 64;
  const float* b = rwb + h * 64;
  float s = 0.f;
#pragma unroll 8
  for (int d = 0; d < 64; ++d) s += (a[d] - b[d]) * (float)rp[d];
  cd[h * 2048 + jr] = s;
}

// ---------------------------------------------------------------------------
// MFMA flash attention v4:
//  - diagonal extraction via per-(tile,reg) __shfl rotate (source lane =
//    (lane&48)|((ln+15-4g-r)&15), same reg) + cndmask select — no f32 scratch,
//    no store->load LDS dependency. cdelta folded at Tf production.
//  - qw staging overlaid into the r ring  -> LDS 46.6 KB -> 3 blocks/CU.
// ---------------------------------------------------------------------------
__global__ __launch_bounds__(256, 3) void attn_mfma4(
    const _Float16* __restrict__ qw16, const _Float16* __restrict__ k16,
    const _Float16* __restrict__ vt16, const _Float16* __restrict__ r16,
    const float* __restrict__ cdelta, _Float16* __restrict__ av16) {
  __shared__ __align__(16) _Float16 k_s[64][72];
  __shared__ __align__(16) _Float16 vt_s[64][72];
  __shared__ __align__(16) _Float16 r_s[128][72];   // ring; qw staged here at phase start
  __shared__ __align__(16) _Float16 P_s[4][16][72];
  __shared__ float cdw_s[128];                      // ring, same slots as r_s

  const int id = blockIdx.x;
  const int hb = id & 63, pr = id >> 6;
  const int h = hb >> 2, b = hb & 3;
  const int bh = b * 16 + h;
  const int t = threadIdx.x;
  const int lane = t & 63, w = t >> 6;
  const int ln = lane & 15, g = lane >> 4;
  const int rb = 48 - 16 * w;          // wave window base within the 128-pos window

  const int s_row4 = t >> 2, s_c16 = (t & 3) * 16;
  const int s_row2 = t >> 1, s_c32 = (t & 1) * 32;

  const float* cdh = cdelta + h * 2048;
  const _Float16* kb_p = k16 + (size_t)bh * 2048 * 64;
  const _Float16* vb_p = vt16 + (size_t)bh * 64 * 2048;
  const _Float16* rb_p = r16 + (size_t)h * 2048 * 64;
  const _Float16* qb_p = qw16 + (size_t)bh * 1024 * 64;

#pragma unroll 1
  for (int phase = 0; phase < 2; ++phase) {
    const int qt = phase ? (15 - pr) : pr;
    const int qbase = qt * 64;
    const int ktiles = qt + 17;
    const int R0 = 960 - qbase;        // global r row of window pos 0 at kt=0 (>=0)

    __syncthreads();                   // prev phase fully done with LDS
    {                                  // stage qw into r_s rows 0..63 (overlay)
      const _Float16* src = qb_p + (size_t)(qbase + s_row4) * 64 + s_c16;
      half8 a0 = *(const half8*)src;
      half8 a1 = *(const half8*)(src + 8);
      *(half8*)&r_s[s_row4][s_c16] = a0;
      *(half8*)&r_s[s_row4][s_c16 + 8] = a1;
    }
    __syncthreads();
    half8 aq0 = *(const half8*)&r_s[16 * w + ln][g * 8];
    half8 aq1 = *(const half8*)&r_s[16 * w + ln][32 + g * 8];
    // (aq reads drain at the kt-loop's first barrier before ring init)

    f32x4 O[4] = {};
    float llane[4] = {0.f, 0.f, 0.f, 0.f};

    half8 kp0, kp1, vp0, vp1, rp0, rp1, rp2, rp3;
    float cdp = 0.f;
    {
      const _Float16* kp = kb_p + (size_t)s_row4 * 64 + s_c16;
      kp0 = *(const half8*)kp; kp1 = *(const half8*)(kp + 8);
      const _Float16* vp = vb_p + (size_t)s_row4 * 2048 + s_c16;
      vp0 = *(const half8*)vp; vp1 = *(const half8*)(vp + 8);
      int rr = R0 + s_row2; rr = rr > 2047 ? 2047 : rr;
      const _Float16* rp = rb_p + (size_t)rr * 64 + s_c32;
      rp0 = *(const half8*)rp;        rp1 = *(const half8*)(rp + 8);
      rp2 = *(const half8*)(rp + 16); rp3 = *(const half8*)(rp + 24);
      if (t < 128) { int cr = R0 + t; cr = cr > 2047 ? 2047 : cr; cdp = cdh[cr]; }
    }

    for (int kt = 0; kt < ktiles; ++kt) {
      const int kbase = kt * 64;
      const int koff = (kt & 1) * 64;  // ring offset for window pos 0
      __syncthreads();
      *(half8*)&k_s[s_row4][s_c16] = kp0;  *(half8*)&k_s[s_row4][s_c16 + 8] = kp1;
      *(half8*)&vt_s[s_row4][s_c16] = vp0; *(half8*)&vt_s[s_row4][s_c16 + 8] = vp1;
      if (kt == 0) {
        *(half8*)&r_s[s_row2][s_c32] = rp0;      *(half8*)&r_s[s_row2][s_c32 + 8] = rp1;
        *(half8*)&r_s[s_row2][s_c32 + 16] = rp2; *(half8*)&r_s[s_row2][s_c32 + 24] = rp3;
        if (t < 128) cdw_s[t] = cdp;
      } else {
        const int sb = 64 - koff;      // this tile's new-rows slot base
        *(half8*)&r_s[sb + s_row4][s_c16] = rp0;
        *(half8*)&r_s[sb + s_row4][s_c16 + 8] = rp1;
        if (t < 64) cdw_s[sb + t] = cdp;
      }
      __syncthreads();
      if (kt + 1 < ktiles) {           // prefetch next tile during compute
        const int kb2 = kbase + 64;
        const _Float16* kp = kb_p + (size_t)(kb2 + s_row4) * 64 + s_c16;
        kp0 = *(const half8*)kp; kp1 = *(const half8*)(kp + 8);
        const _Float16* vp = vb_p + (size_t)s_row4 * 2048 + kb2 + s_c16;
        vp0 = *(const half8*)vp; vp1 = *(const half8*)(vp + 8);
        int rr = R0 + kbase + 128 + s_row4; rr = rr > 2047 ? 2047 : rr;
        const _Float16* rp = rb_p + (size_t)rr * 64 + s_c16;
        rp0 = *(const half8*)rp; rp1 = *(const half8*)(rp + 8);
        if (t < 64) { int cr = R0 + kbase + 128 + t; cr = cr > 2047 ? 2047 : cr; cdp = cdh[cr]; }
      }

      // ---- QK^T: 4 j-tiles ----
      f32x4 Sf[4];
#pragma unroll
      for (int jt = 0; jt < 4; ++jt) {
        half8 b0 = *(const half8*)&k_s[jt * 16 + ln][g * 8];
        half8 b1 = *(const half8*)&k_s[jt * 16 + ln][32 + g * 8];
        f32x4 z = {0.f, 0.f, 0.f, 0.f};
        z = __builtin_amdgcn_mfma_f32_16x16x32_f16(aq0, b0, z, 0, 0, 0);
        z = __builtin_amdgcn_mfma_f32_16x16x32_f16(aq1, b1, z, 0, 0, 0);
        Sf[jt] = z;
      }
      // ---- T window (5 col-tiles of 16), cdelta folded at production ----
      f32x4 Tf[5];
#pragma unroll
      for (int ft = 0; ft < 5; ++ft) {
        int rrow = (rb + ft * 16 + ln + koff) & 127;
        half8 b0 = *(const half8*)&r_s[rrow][g * 8];
        half8 b1 = *(const half8*)&r_s[rrow][32 + g * 8];
        f32x4 z = {0.f, 0.f, 0.f, 0.f};
        z = __builtin_amdgcn_mfma_f32_16x16x32_f16(aq0, b0, z, 0, 0, 0);
        z = __builtin_amdgcn_mfma_f32_16x16x32_f16(aq1, b1, z, 0, 0, 0);
        float cdv = cdw_s[rrow];
        z[0] += cdv; z[1] += cdv; z[2] += cdv; z[3] += cdv;
        Tf[ft] = z;
      }
      // ---- diagonal via shfl rotate + select; exp; P_s; l ----
      const int climit = qbase + 16 * w + 1039 - kbase;
#pragma unroll
      for (int r = 0; r < 4; ++r) {
        const int c = 15 - 4 * g - r;       // in [0,15]
        const int lnc = ln + c;             // in [0,30]
        const int src = (lane & 48) | (lnc & 15);
        float rot[5];
#pragma unroll
        for (int ft = 0; ft < 5; ++ft) rot[ft] = __shfl(Tf[ft][r], src, 64);
        const bool hi = lnc >= 16;
        float psum = 0.f;
#pragma unroll
        for (int jt = 0; jt < 4; ++jt) {
          float tv = hi ? rot[jt + 1] : rot[jt];
          float x = (Sf[jt][r] + tv) * 0.125f;
          int cw = jt * 16 + lnc;
          float p = (cw > climit) ? 0.f : __expf(x);
          psum += p;
          P_s[w][4 * g + r][jt * 16 + ln] = (_Float16)p;
        }
        llane[r] += psum;
      }
      // ---- PV ----
      half8 pA0 = *(const half8*)&P_s[w][ln][g * 8];
      half8 pA1 = *(const half8*)&P_s[w][ln][32 + g * 8];
#pragma unroll
      for (int dt = 0; dt < 4; ++dt) {
        half8 b0 = *(const half8*)&vt_s[dt * 16 + ln][g * 8];
        half8 b1 = *(const half8*)&vt_s[dt * 16 + ln][32 + g * 8];
        O[dt] = __builtin_amdgcn_mfma_f32_16x16x32_f16(pA0, b0, O[dt], 0, 0, 0);
        O[dt] = __builtin_amdgcn_mfma_f32_16x16x32_f16(pA1, b1, O[dt], 0, 0, 0);
      }
    }

    // ---- epilogue ----
#pragma unroll
    for (int r = 0; r < 4; ++r) {
      float ls = llane[r];
      ls += __shfl_xor(ls, 1, 64);
      ls += __shfl_xor(ls, 2, 64);
      ls += __shfl_xor(ls, 4, 64);
      ls += __shfl_xor(ls, 8, 64);
      float inv = 1.f / ls;
      int qrow = qbase + 16 * w + 4 * g + r;
      _Float16* op = av16 + ((size_t)b * 1024 + qrow) * 1024 + h * 64 + ln;
#pragma unroll
      for (int dt = 0; dt < 4; ++dt) op[dt * 16] = (_Float16)(O[dt][r] * inv);
    }
  }
}

// ---------------------------------------------------------------------------
extern "C" void kernel_launch(void* const* d_in, const int* in_sizes, int n_in,
                              void* d_out, int out_size, void* d_ws, size_t ws_size,
                              hipStream_t stream) {
  const float* inputs  = (const float*)d_in[0];
  const float* pos_emb = (const float*)d_in[1];
  const float* rwb     = (const float*)d_in[2];
  const float* rrb     = (const float*)d_in[3];
  const float* mems    = (const float*)d_in[4];
  const float* W_w     = (const float*)d_in[5];
  const float* W_r     = (const float*)d_in[6];
  const float* W_o     = (const float*)d_in[7];
  float* out = (float*)d_out;

  _Float16* hws = (_Float16*)d_ws;
  _Float16* a16   = hws;                                    // 8192*1024
  _Float16* pe16  = a16  + (size_t)8192 * 1024;             // 2048*1024
  _Float16* qw16  = pe16 + (size_t)2048 * 1024;             // 64*1024*64
  _Float16* k16   = qw16 + (size_t)64 * 1024 * 64;          // 64*2048*64
  _Float16* vt16  = k16  + (size_t)64 * 2048 * 64;          // 64*64*2048
  _Float16* r16   = vt16 + (size_t)64 * 64 * 2048;          // 16*2048*64
  _Float16* av16  = r16  + (size_t)16 * 2048 * 64;          // 4096*1024
  _Float16* wwt   = av16 + (size_t)4096 * 1024;             // 3072*2048
  _Float16* wrt   = wwt  + (size_t)3072 * 2048;             // 1024*2048
  _Float16* wot   = wrt  + (size_t)1024 * 2048;             // 1024*2048
  float*    cdelta = (float*)(wot + (size_t)1024 * 2048);   // 16*2048 f32

  // 0) input conversions + weight splits (merged launches)
  convert_all<<<10240, 256, 0, stream>>>(mems, inputs, pos_emb, a16, pe16);
  split_w3<<<dim3(80, 16), 256, 0, stream>>>(W_w, W_r, W_o, wwt, wrt, wot);
  // 1) qkv = cat @ W_w (1-term fp16), fused scatter to qw16/k16/vt16
  gemm2<<<dim3(24, 64), 256, 0, stream>>>(a16, wwt, 0, rwb, qw16, k16, vt16, nullptr);
  // 2) r16 = pos_emb @ W_r (1-term fp16)
  gemm2<<<dim3(8, 16), 256, 0, stream>>>(pe16, wrt, 1, rwb, r16, nullptr, nullptr, nullptr);
  // 3) cdelta
  cdelta_kernel<<<128, 256, 0, stream>>>(r16, rwb, rrb, cdelta);
  // 4) MFMA flash attention v4 (shfl diag, 3 blocks/CU)
  attn_mfma4<<<512, 256, 0, stream>>>(qw16, k16, vt16, r16, cdelta, av16);
  // 5) out = av16 @ W_o (2-term, fp32 out)
  gemm2<<<dim3(8, 32), 256, 0, stream>>>(av16, wot, 2, rwb, nullptr, nullptr, nullptr, out);
}